// Round 7
// baseline (78.272 us; speedup 1.0000x reference)
//
#include <hip/hip_runtime.h>

// CostVolume: out (1, 2C, D4, H, W) fp32
//   c <  C : left [c,h,w]     if w >= d else 0
//   c >= C : right[c-C,h,w-d] if w >= d else 0
// C=32, H=128, W=240, D4=48.  Write-BW-bound: 377.5 MB out.
//
// R6: NT vs plain stores = no change; traffic already ideal (377.5 MB
// written, 3.9 MB fetched). Stuck at 4.87 TB/s vs fill's 6.86 TB/s.
// DIAGNOSTIC ROUND: split left (pure reg-replay, store-pure) and right
// (LDS shifted reads) into separate dispatches to see per-path BW in the
// kernel trace and probe for fixed per-dispatch overhead.

constexpr int C   = 32;
constexpr int H   = 128;
constexpr int W   = 240;
constexpr int D4  = 48;
constexpr int W4  = W / 4;            // 60 float4 per row
constexpr int RPB = 8;                // rows per block
constexpr int HC  = H / RPB;          // 16 h-chunks
constexpr int CH4 = RPB * W4;         // 480 float4 per chunk
constexpr int BLOCK = 256;
constexpr int PAD_OFF = 48;           // guard so (w - d) reads stay >= 0

typedef float f32x4 __attribute__((ext_vector_type(4)));

__device__ __forceinline__ int pidx(int x) { return x + (x >> 5); }

// ---------------- LEFT: source float4 == output float4, masked replay ------
__global__ void __launch_bounds__(256) cv_left_kernel(
    const float* __restrict__ left, float* __restrict__ out) {
    const int blk = blockIdx.x;        // c2*HC + hc, c2 in [0,32)
    const int hc  = blk % HC;
    const int c2  = blk / HC;
    const int h0  = hc * RPB;
    const int tid = threadIdx.x;

    f32x4* __restrict__ outb = reinterpret_cast<f32x4*>(out)
        + ((long)(c2 * D4) * H + h0) * W4;
    const long dstride = (long)H * W4;

    const int f0  = tid;
    const int f1  = tid + BLOCK;
    const bool has1 = (f1 < CH4);
    const int f1c = has1 ? f1 : (CH4 - 1);
    const int w0_0 = (f0 % W4) * 4;
    const int w0_1 = (f1c % W4) * 4;

    const f32x4* __restrict__ src4 =
        reinterpret_cast<const f32x4*>(left + (c2 * H + h0) * W);
    const f32x4 t0 = src4[f0];
    const f32x4 t1 = has1 ? src4[f1] : f32x4{0.f, 0.f, 0.f, 0.f};
#pragma unroll 4
    for (int d = 0; d < D4; ++d) {
        f32x4 v0, v1;
#pragma unroll
        for (int j = 0; j < 4; ++j) {
            v0[j] = (w0_0 + j >= d) ? t0[j] : 0.0f;
            v1[j] = (w0_1 + j >= d) ? t1[j] : 0.0f;
        }
        f32x4* __restrict__ o = outb + d * dstride;
        o[f0] = v0;
        if (has1) o[f1] = v1;
    }
}

// ---------------- RIGHT: LDS-staged rows, shifted reads ---------------------
__global__ void __launch_bounds__(256) cv_right_kernel(
    const float* __restrict__ right, float* __restrict__ out) {
    __shared__ float rowbuf[2080];

    const int blk = blockIdx.x;        // cr*HC + hc, cr in [0,32)
    const int hc  = blk % HC;
    const int cr  = blk / HC;
    const int c2  = cr + C;            // output channel
    const int h0  = hc * RPB;
    const int tid = threadIdx.x;

    f32x4* __restrict__ outb = reinterpret_cast<f32x4*>(out)
        + ((long)(c2 * D4) * H + h0) * W4;
    const long dstride = (long)H * W4;

    const int f0  = tid;
    const int f1  = tid + BLOCK;
    const bool has1 = (f1 < CH4);
    const int f1c = has1 ? f1 : (CH4 - 1);
    const int w0_0 = (f0 % W4) * 4;
    const int w0_1 = (f1c % W4) * 4;

    const float* __restrict__ src = right + (cr * H + h0) * W;
    for (int f = tid; f < CH4; f += BLOCK) {
        f32x4 t = reinterpret_cast<const f32x4*>(src)[f];
        const int base = PAD_OFF + f * 4;
#pragma unroll
        for (int j = 0; j < 4; ++j) rowbuf[pidx(base + j)] = t[j];
    }
    __syncthreads();
    const int b0 = PAD_OFF + (f0  / W4) * W + w0_0;
    const int b1 = PAD_OFF + (f1c / W4) * W + w0_1;
#pragma unroll 4
    for (int d = 0; d < D4; ++d) {
        f32x4 v0, v1;
#pragma unroll
        for (int j = 0; j < 4; ++j) {
            v0[j] = (w0_0 + j >= d) ? rowbuf[pidx(b0 - d + j)] : 0.0f;
            v1[j] = (w0_1 + j >= d) ? rowbuf[pidx(b1 - d + j)] : 0.0f;
        }
        f32x4* __restrict__ o = outb + d * dstride;
        o[f0] = v0;
        if (has1) o[f1] = v1;
    }
}

extern "C" void kernel_launch(void* const* d_in, const int* in_sizes, int n_in,
                              void* d_out, int out_size, void* d_ws,
                              size_t ws_size, hipStream_t stream) {
    const float* left  = (const float*)d_in[0];
    const float* right = (const float*)d_in[1];
    float* out = (float*)d_out;

    const int grid = C * HC;   // 512 blocks each half
    cv_left_kernel <<<grid, BLOCK, 0, stream>>>(left, out);
    cv_right_kernel<<<grid, BLOCK, 0, stream>>>(right, out);
}